// Round 5
// baseline (634.330 us; speedup 1.0000x reference)
//
#include <hip/hip_runtime.h>

// Problem constants (all verified by round-4 probe: fp32 in, fp32 out)
#define BT    32768          // B*T rows
#define CD    512            // feature dim
#define KC    1024           // codebook size
// Output layout (fp32 elements): quant[16777216], cb[16], cm[16], idx[32768]
#define LOFF1 16777216
#define LOFF2 16777232
#define IOFF  16777248
// ws layout (bytes); probe says ws_size >= 4 MB
#define WS_KWIN 0            // int kwin[32768]
#define WS_PART 131072       // float part[512]

#define MT 64
#define NT 256
#define CT 16

// ---------------- Kernel 1: fused distance GEMM + top-2 + fp64 refine --------
// Grid 512 (M-tiles of 64 rows) x 256 threads. fp32 register-tile GEMM for
// e2 - 2*x.e (e2 accumulated on the fly), per-block top-2 argmin per row,
// exact fp64 refine of both candidates, fp32 idx write, loss partial to ws.
__global__ __launch_bounds__(256, 2) void argmin_kernel(
    const float* __restrict__ x, const float* __restrict__ emb,
    float* __restrict__ out, int* __restrict__ kwin, float* __restrict__ part) {
  __shared__ float As[CT][MT];     // 4 KB
  __shared__ float Bs[CT][NT];     // 16 KB
  __shared__ float e2s[NT];        // 1 KB
  __shared__ float rv0[32][MT];    // 8 KB
  __shared__ int   ri0[32][MT];    // 8 KB
  __shared__ float rv1[32][MT];    // 8 KB
  __shared__ int   ri1[32][MT];    // 8 KB
  __shared__ int    canda[MT], candb[MT];
  __shared__ double dex[2][MT];
  __shared__ float  q2x[2][MT], xqx[2][MT], x2x[MT];

  const int tid = threadIdx.x;
  const int m0  = blockIdx.x * MT;
  const int tr  = tid & 7;    // rows tr*8 .. tr*8+7
  const int tk  = tid >> 3;   // codes tk*8 .. tk*8+7 within N-tile
  const int arow = tid >> 2;  // 0..63 (A staging row)
  const int ac4  = tid & 3;   // 0..3  (A staging float4 chunk)

  float b0[8], b1[8];
  int   i0[8], i1[8];
#pragma unroll
  for (int i = 0; i < 8; ++i) { b0[i] = 3.4e38f; b1[i] = 3.4e38f; i0[i] = 0; i1[i] = 0; }

  float e2acc = 0.f;   // running ||emb[n-tile code tid]||^2 per tile

  for (int nt = 0; nt < KC / NT; ++nt) {
    const int n0 = nt * NT;
    float acc[8][8];
#pragma unroll
    for (int i = 0; i < 8; ++i)
#pragma unroll
      for (int j = 0; j < 8; ++j) acc[i][j] = 0.f;
    e2acc = 0.f;

    for (int ct = 0; ct < CD / CT; ++ct) {
      const int c0 = ct * CT;
      __syncthreads();
      // A tile: 64 rows x 16 c, one float4 per thread, transposed store
      {
        float4 av = *reinterpret_cast<const float4*>(
            x + (size_t)(m0 + arow) * CD + c0 + ac4 * 4);
        As[ac4*4+0][arow] = av.x;
        As[ac4*4+1][arow] = av.y;
        As[ac4*4+2][arow] = av.z;
        As[ac4*4+3][arow] = av.w;
      }
      // B tile: code n0+tid, 16 c = 4 float4, transposed store + e2 on the fly
      {
        const float4* bp = reinterpret_cast<const float4*>(
            emb + (size_t)(n0 + tid) * CD + c0);
#pragma unroll
        for (int i = 0; i < 4; ++i) {
          float4 q = bp[i];
          Bs[i*4+0][tid] = q.x; Bs[i*4+1][tid] = q.y;
          Bs[i*4+2][tid] = q.z; Bs[i*4+3][tid] = q.w;
          e2acc += q.x*q.x + q.y*q.y + q.z*q.z + q.w*q.w;
        }
      }
      __syncthreads();
#pragma unroll
      for (int c = 0; c < CT; ++c) {
        float a[8], b[8];
        *reinterpret_cast<float4*>(&a[0]) = *reinterpret_cast<const float4*>(&As[c][tr*8]);
        *reinterpret_cast<float4*>(&a[4]) = *reinterpret_cast<const float4*>(&As[c][tr*8+4]);
        *reinterpret_cast<float4*>(&b[0]) = *reinterpret_cast<const float4*>(&Bs[c][tk*8]);
        *reinterpret_cast<float4*>(&b[4]) = *reinterpret_cast<const float4*>(&Bs[c][tk*8+4]);
#pragma unroll
        for (int i = 0; i < 8; ++i)
#pragma unroll
          for (int j = 0; j < 8; ++j)
            acc[i][j] += a[i] * b[j];
      }
    }
    e2s[tid] = e2acc;
    __syncthreads();
    // fold into running top-2 (k ascending -> first-min kept on ties)
#pragma unroll
    for (int j = 0; j < 8; ++j) {
      const int kl = tk * 8 + j;
      const int k  = n0 + kl;
      const float ek = e2s[kl];
#pragma unroll
      for (int i = 0; i < 8; ++i) {
        const float d = ek - 2.f * acc[i][j];
        if (d < b0[i])      { b1[i] = b0[i]; i1[i] = i0[i]; b0[i] = d; i0[i] = k; }
        else if (d < b1[i]) { b1[i] = d; i1[i] = k; }
      }
    }
    __syncthreads();   // e2s reused next tile
  }

#pragma unroll
  for (int i = 0; i < 8; ++i) {
    rv0[tk][tr*8+i] = b0[i];  ri0[tk][tr*8+i] = i0[i];
    rv1[tk][tr*8+i] = b1[i];  ri1[tk][tr*8+i] = i1[i];
  }
  __syncthreads();
  if (tid < MT) {
    float bv0 = rv0[0][tid]; int bi0 = ri0[0][tid];
    float bv1 = rv1[0][tid]; int bi1 = ri1[0][tid];
    for (int t = 1; t < 32; ++t) {
#pragma unroll
      for (int s = 0; s < 2; ++s) {
        const float v = s ? rv1[t][tid] : rv0[t][tid];
        const int   i = s ? ri1[t][tid] : ri0[t][tid];
        if (v < bv0 || (v == bv0 && i < bi0)) {
          bv1 = bv0; bi1 = bi0; bv0 = v; bi0 = i;
        } else if (v < bv1 || (v == bv1 && i < bi1)) {
          bv1 = v; bi1 = i;
        }
      }
    }
    canda[tid] = bi0 & (KC - 1);
    candb[tid] = bi1 & (KC - 1);
  }
  __syncthreads();

  // ---- exact fp64 refine of the two candidates (threads 0..127) ----
  if (tid < 128) {
    const int w = tid >> 6, row = tid & 63, gr = m0 + row;
    const int k = w ? candb[row] : canda[row];
    const float4* xr = reinterpret_cast<const float4*>(x   + (size_t)gr * CD);
    const float4* er = reinterpret_cast<const float4*>(emb + (size_t)k  * CD);
    double d = 0.0;
    float sq2 = 0.f, sxq = 0.f, sx2 = 0.f;
    for (int c4 = 0; c4 < CD / 4; ++c4) {
      const float4 a = xr[c4], b = er[c4];
      const float xa[4] = {a.x, a.y, a.z, a.w};
      const float ea[4] = {b.x, b.y, b.z, b.w};
#pragma unroll
      for (int j = 0; j < 4; ++j) {
        const double t = (double)xa[j] - (double)ea[j];
        d += t * t;
        sq2 += ea[j]*ea[j]; sxq += xa[j]*ea[j]; sx2 += xa[j]*xa[j];
      }
    }
    dex[w][row] = d;
    q2x[w][row] = sq2;
    xqx[w][row] = sxq;
    if (!w) x2x[row] = sx2;
  }
  __syncthreads();

  // ---- winner pick + fp32 idx write + block loss partial (wave 0) ----
  if (tid < MT) {
    const int row = tid, gr = m0 + row;
    const int ka = canda[row], kb = candb[row];
    const double da = dex[0][row], db = dex[1][row];
    int wi;
    if (da < db)      wi = 0;
    else if (db < da) wi = 1;
    else              wi = (ka <= kb) ? 0 : 1;
    const int kf = wi ? kb : ka;
    out[IOFF + gr] = (float)kf;     // fp32 index value
    kwin[gr] = kf;

    const float q2 = wi ? q2x[1][row] : q2x[0][row];
    const float xq = wi ? xqx[1][row] : xqx[0][row];
    const float x2 = x2x[row];
    const float nx = fmaxf(sqrtf(x2), 1e-5f);
    const float nq = fmaxf(sqrtf(q2), 1e-5f);
    float s = q2/(nq*nq) + x2/(nx*nx) - 2.f*xq/(nx*nq);
    for (int off = 32; off > 0; off >>= 1) s += __shfl_down(s, off, 64);
    if (tid == 0) part[blockIdx.x] = s;
  }
}

// ---------------- Kernel 2: gather + fp32 quant write ------------------------
// One wave per row (4 rows/block): quant_out = emb[k] (straight-through fwd).
__global__ __launch_bounds__(256) void gather_kernel(
    const float* __restrict__ emb, const int* __restrict__ kwin,
    float* __restrict__ out) {
  const int lane = threadIdx.x & 63;
  const int r    = blockIdx.x * 4 + (threadIdx.x >> 6);
  const int k    = kwin[r] & (KC - 1);
  const float4* er = reinterpret_cast<const float4*>(emb + (size_t)k * CD);
  float4* qr = reinterpret_cast<float4*>(out + (size_t)r * CD);
  qr[lane*2]   = er[lane*2];
  qr[lane*2+1] = er[lane*2+1];
}

// ---------------- Kernel 3: reduce block partials -> both losses -------------
// Blocks 32b..32b+31 cover batch b (64 rows/block, 2048 rows/batch).
__global__ void loss_write_kernel(const float* __restrict__ part,
                                  float* __restrict__ out) {
  const int t = threadIdx.x;
  if (t < 16) {
    float acc = 0.f;
    for (int i = 0; i < 32; ++i) acc += part[32*t + i];
    const float v = acc * (1.f / 1048576.f);   // / (T*C)
    out[LOFF1 + t] = v;
    out[LOFF2 + t] = v;
  }
}

extern "C" void kernel_launch(void* const* d_in, const int* in_sizes, int n_in,
                              void* d_out, int out_size, void* d_ws, size_t ws_size,
                              hipStream_t stream) {
  const float* x   = (const float*)d_in[0];   // [16,2048,512] fp32
  const float* emb = (const float*)d_in[1];   // [1024,512] fp32
  float* out = (float*)d_out;                 // fp32, 16810016 elements

  int*   kwin = (int*)((char*)d_ws + WS_KWIN);
  float* part = (float*)((char*)d_ws + WS_PART);

  argmin_kernel<<<BT / MT, 256, 0, stream>>>(x, emb, out, kwin, part);
  gather_kernel<<<BT / 4, 256, 0, stream>>>(emb, kwin, out);
  loss_write_kernel<<<1, 64, 0, stream>>>(part, out);
}

// Round 6
// 258.176 us; speedup vs baseline: 2.4570x; 2.4570x over previous
//
#include <hip/hip_runtime.h>

typedef unsigned short u16;
typedef unsigned int u32;
typedef _Float16 half8 __attribute__((ext_vector_type(8)));
typedef float f32x4 __attribute__((ext_vector_type(4)));

// Problem constants (verified: fp32 in, fp32 out buffer of 16810016 elems)
#define BT    32768
#define CD    512
#define KC    1024
#define LOFF1 16777216
#define LOFF2 16777232
#define IOFF  16777248

// ws layout (bytes); ws >= 4 MB (probe round 4)
#define WS_EH   0          // u16 eh[1024*512]  (1 MB)
#define WS_E2   1048576    // float e2[1024]
#define WS_KW   1052672    // int kwin[32768]   (128 KB)
#define WS_PART 1183744    // float part[512]

static __device__ __forceinline__ u16 f2h(float f) {
  union { _Float16 h; u16 u; } c;
  c.h = (_Float16)f;
  return c.u;
}

static __device__ __forceinline__ void gload16(const void* g, void* l) {
  __builtin_amdgcn_global_load_lds(
      (const __attribute__((address_space(1))) u32*)g,
      (__attribute__((address_space(3))) u32*)l, 16, 0, 0);
}

// ---------------- Kernel 1a: convert x fp32 -> fp16 (into out quant region) --
__global__ __launch_bounds__(256) void convx_kernel(const float4* __restrict__ x4,
                                                    uint2* __restrict__ xh2) {
  const int i = blockIdx.x * 256 + threadIdx.x;
  const float4 v = x4[i];
  uint2 o;
  o.x = (u32)f2h(v.x) | ((u32)f2h(v.y) << 16);
  o.y = (u32)f2h(v.z) | ((u32)f2h(v.w) << 16);
  xh2[i] = o;
}

// ---------------- Kernel 1b: convert emb -> fp16 + exact fp32 e2 -------------
__global__ __launch_bounds__(256) void conve_kernel(const float* __restrict__ emb,
                                                    u16* __restrict__ eh,
                                                    float* __restrict__ e2) {
  const int lane = threadIdx.x & 63;
  const int r    = blockIdx.x * 4 + (threadIdx.x >> 6);
  const float4* er = reinterpret_cast<const float4*>(emb + (size_t)r * CD);
  const float4 a = er[lane*2], b = er[lane*2+1];
  uint4 o;
  o.x = (u32)f2h(a.x) | ((u32)f2h(a.y) << 16);
  o.y = (u32)f2h(a.z) | ((u32)f2h(a.w) << 16);
  o.z = (u32)f2h(b.x) | ((u32)f2h(b.y) << 16);
  o.w = (u32)f2h(b.z) | ((u32)f2h(b.w) << 16);
  reinterpret_cast<uint4*>(eh + (size_t)r * CD)[lane] = o;
  float s = a.x*a.x + a.y*a.y + a.z*a.z + a.w*a.w
          + b.x*b.x + b.y*b.y + b.z*b.z + b.w*b.w;
  for (int off = 32; off > 0; off >>= 1) s += __shfl_down(s, off, 64);
  if (lane == 0) e2[r] = s;
}

// ---------------- Kernel 2: MFMA distance + top-4 capture + fp64 refine ------
// Block = 64 rows, 256 threads (4 waves). Wave wv covers cols wv*64 of each
// 256-col N-tile (nt = 0..3). K-loop: 16 steps of 32, fragment-major LDS
// tiles staged via global_load_lds(16B). Per-lane packed top-2, LDS merge to
// top-4 per row, exact fp64 refine, winner -> idx/kwin/loss partial.
__global__ __launch_bounds__(256) void mfma_argmin_kernel(
    const u16* __restrict__ xh, const u16* __restrict__ eh,
    const float* __restrict__ e2, const float* __restrict__ x,
    const float* __restrict__ emb, float* __restrict__ out,
    int* __restrict__ kwin, float* __restrict__ part) {
  __shared__ __align__(16) char smem[38400];
  u16*   sA   = (u16*)smem;             // 4 tiles * 512 u16 = 4 KB
  u16*   sB   = (u16*)(smem + 4096);    // 16 tiles * 512 u16 = 16 KB
  float* e2s  = (float*)(smem + 20480); // 256 floats
  u32*   cand = (u32*)smem;             // REUSED after K-loops: [64][128]
  int*   top4k = (int*)(smem + 32768);  // [64][4]
  double* dref = (double*)(smem + 33792); // [64][4]
  float* q2a  = (float*)(smem + 35840); // [64][4]
  float* xqa  = (float*)(smem + 36864); // [64][4]
  float* x2a  = (float*)(smem + 37888); // [64]

  const int tid  = threadIdx.x;
  const int wv   = tid >> 6;
  const int lane = tid & 63;
  const int lm   = lane & 15;   // fragment m/n index
  const int lq   = lane >> 4;   // fragment k-chunk (quad)
  const int m0   = blockIdx.x * 64;

  u32 t0[16], t1[16];
#pragma unroll
  for (int s = 0; s < 16; ++s) { t0[s] = 0xFFFFFFFFu; t1[s] = 0xFFFFFFFFu; }

  // wave wv stages A tile ti=wv: global row = m0 + wv*16 + lm, k-chunk lq
  const u16* gA = xh + (size_t)(m0 + wv*16 + lm) * CD + lq*8;

  for (int nt = 0; nt < 4; ++nt) {
    __syncthreads();                 // prev nt's e2s readers done
    e2s[tid] = e2[nt*256 + tid];

    f32x4 acc[4][4];
#pragma unroll
    for (int i = 0; i < 4; ++i)
#pragma unroll
      for (int j = 0; j < 4; ++j)
        acc[i][j] = (f32x4){0.f, 0.f, 0.f, 0.f};

    for (int ks = 0; ks < 16; ++ks) {
      __syncthreads();               // prev frag reads done before overwrite
      gload16(gA + ks*32, sA + wv*512);
#pragma unroll
      for (int tjl = 0; tjl < 4; ++tjl) {
        const u16* gB = eh + (size_t)(nt*256 + wv*64 + tjl*16 + lm) * CD + ks*32 + lq*8;
        gload16(gB, sB + (wv*4 + tjl)*512);
      }
      __syncthreads();               // compiler drains vmcnt before barrier
      half8 bf[4];
#pragma unroll
      for (int tjl = 0; tjl < 4; ++tjl)
        bf[tjl] = *(const half8*)(sB + (wv*4 + tjl)*512 + lane*8);
#pragma unroll
      for (int ti = 0; ti < 4; ++ti) {
        const half8 af = *(const half8*)(sA + ti*512 + lane*8);
#pragma unroll
        for (int tjl = 0; tjl < 4; ++tjl)
          acc[ti][tjl] = __builtin_amdgcn_mfma_f32_16x16x32_f16(
              af, bf[tjl], acc[ti][tjl], 0, 0, 0);
      }
    }

    // fold this nt's 64 cols/lane into packed top-2 per row-slot
#pragma unroll
    for (int tjl = 0; tjl < 4; ++tjl) {
      const float ek = e2s[wv*64 + tjl*16 + lm];
      const u32 col  = (u32)(nt*256 + wv*64 + tjl*16 + lm);
#pragma unroll
      for (int ti = 0; ti < 4; ++ti)
#pragma unroll
        for (int reg = 0; reg < 4; ++reg) {
          const float d = ek - 2.f * acc[ti][tjl][reg] + 1024.f;  // shift>0
          const u32 p = (__float_as_uint(d) & 0xFFFFFC00u) | col;
          const int s = ti*4 + reg;
          if (p < t0[s]) { t1[s] = t0[s]; t0[s] = p; }
          else if (p < t1[s]) { t1[s] = p; }
        }
    }
  }

  __syncthreads();   // all frag reads of sA/sB complete before cand reuse
#pragma unroll
  for (int s = 0; s < 16; ++s) {
    const int ti = s >> 2, reg = s & 3;
    const int row = ti*16 + lq*4 + reg;
    uint2 pr; pr.x = t0[s]; pr.y = t1[s];
    *reinterpret_cast<uint2*>(&cand[row*128 + wv*32 + lm*2]) = pr;
  }
  __syncthreads();

  // ---- merge 128 candidates -> top-4 per row (threads 0..63) ----
  if (tid < 64) {
    u32 u0 = 0xFFFFFFFFu, u1 = 0xFFFFFFFFu, u2 = 0xFFFFFFFFu, u3 = 0xFFFFFFFFu;
    for (int i = 0; i < 128; ++i) {
      const u32 v = cand[tid*128 + ((i + tid*2) & 127)];
      if (v < u3) {
        if (v < u2) {
          u3 = u2;
          if (v < u1) {
            u2 = u1;
            if (v < u0) { u1 = u0; u0 = v; } else { u1 = v; }
          } else { u2 = v; }
        } else { u3 = v; }
      }
    }
    top4k[tid*4+0] = (int)(u0 & 1023u);
    top4k[tid*4+1] = (int)(u1 & 1023u);
    top4k[tid*4+2] = (int)(u2 & 1023u);
    top4k[tid*4+3] = (int)(u3 & 1023u);
  }
  __syncthreads();

  // ---- exact fp64 refine: thread = (row, cand) ----
  {
    const int rr = tid >> 2, cc = tid & 3;
    const int k = top4k[rr*4 + cc];
    const float4* xr = reinterpret_cast<const float4*>(x   + (size_t)(m0+rr) * CD);
    const float4* er = reinterpret_cast<const float4*>(emb + (size_t)k * CD);
    double d0 = 0.0, d1 = 0.0;
    float q2 = 0.f, xq = 0.f, x2 = 0.f;
    for (int i = 0; i < CD/4; ++i) {
      const float4 a = xr[i], b = er[i];
      const double ta = (double)a.x - (double)b.x;
      const double tb = (double)a.y - (double)b.y;
      const double tc = (double)a.z - (double)b.z;
      const double td = (double)a.w - (double)b.w;
      d0 += ta*ta + tc*tc;
      d1 += tb*tb + td*td;
      q2 += b.x*b.x + b.y*b.y + b.z*b.z + b.w*b.w;
      xq += a.x*b.x + a.y*b.y + a.z*b.z + a.w*b.w;
      x2 += a.x*a.x + a.y*a.y + a.z*a.z + a.w*a.w;
    }
    dref[rr*4 + cc] = d0 + d1;
    q2a[rr*4 + cc] = q2;
    xqa[rr*4 + cc] = xq;
    if (cc == 0) x2a[rr] = x2;
  }
  __syncthreads();

  // ---- winner pick + outputs (wave 0, 64 lanes = 64 rows) ----
  if (tid < 64) {
    double bd = dref[tid*4]; int bk = top4k[tid*4]; int bc = 0;
#pragma unroll
    for (int c = 1; c < 4; ++c) {
      const double dc = dref[tid*4 + c];
      const int kc = top4k[tid*4 + c];
      if (dc < bd || (dc == bd && kc < bk)) { bd = dc; bk = kc; bc = c; }
    }
    const int gr = m0 + tid;
    out[IOFF + gr] = (float)bk;
    kwin[gr] = bk;

    const float q2 = q2a[tid*4 + bc];
    const float xq = xqa[tid*4 + bc];
    const float x2 = x2a[tid];
    const float nx = fmaxf(sqrtf(x2), 1e-5f);
    const float nq = fmaxf(sqrtf(q2), 1e-5f);
    float s = q2/(nq*nq) + x2/(nx*nx) - 2.f*xq/(nx*nq);
    for (int off = 32; off > 0; off >>= 1) s += __shfl_down(s, off, 64);
    if (tid == 0) part[blockIdx.x] = s;
  }
}

// ---------------- Kernel 3: gather + fp32 quant write ------------------------
__global__ __launch_bounds__(256) void gather_kernel(
    const float* __restrict__ emb, const int* __restrict__ kwin,
    float* __restrict__ out) {
  const int lane = threadIdx.x & 63;
  const int r    = blockIdx.x * 4 + (threadIdx.x >> 6);
  const int k    = kwin[r] & (KC - 1);
  const float4* er = reinterpret_cast<const float4*>(emb + (size_t)k * CD);
  float4* qr = reinterpret_cast<float4*>(out + (size_t)r * CD);
  qr[lane*2]   = er[lane*2];
  qr[lane*2+1] = er[lane*2+1];
}

// ---------------- Kernel 4: reduce block partials -> both losses -------------
__global__ void loss_write_kernel(const float* __restrict__ part,
                                  float* __restrict__ out) {
  const int t = threadIdx.x;
  if (t < 16) {
    float acc = 0.f;
    for (int i = 0; i < 32; ++i) acc += part[32*t + i];
    const float v = acc * (1.f / 1048576.f);   // / (T*C)
    out[LOFF1 + t] = v;
    out[LOFF2 + t] = v;
  }
}

extern "C" void kernel_launch(void* const* d_in, const int* in_sizes, int n_in,
                              void* d_out, int out_size, void* d_ws, size_t ws_size,
                              hipStream_t stream) {
  const float* x   = (const float*)d_in[0];   // [16,2048,512] fp32
  const float* emb = (const float*)d_in[1];   // [1024,512] fp32
  float* out = (float*)d_out;

  u16*   eh   = (u16*)((char*)d_ws + WS_EH);
  float* e2   = (float*)((char*)d_ws + WS_E2);
  int*   kwin = (int*)((char*)d_ws + WS_KW);
  float* part = (float*)((char*)d_ws + WS_PART);
  u16*   xh   = (u16*)out;   // 33.5 MB scratch inside the 67 MB quant region

  convx_kernel<<<BT * CD / 4 / 256, 256, 0, stream>>>(
      (const float4*)x, (uint2*)xh);
  conve_kernel<<<KC / 4, 256, 0, stream>>>(emb, eh, e2);
  mfma_argmin_kernel<<<BT / 64, 256, 0, stream>>>(
      xh, eh, e2, x, emb, out, kwin, part);
  gather_kernel<<<BT / 4, 256, 0, stream>>>(emb, kwin, out);
  loss_write_kernel<<<1, 64, 0, stream>>>(part, out);
}